// Round 22
// baseline (471.229 us; speedup 1.0000x reference)
//
#include <hip/hip_runtime.h>
#include <stdint.h>

using f16 = _Float16;
typedef __attribute__((ext_vector_type(8))) f16 f16x8;
typedef __attribute__((ext_vector_type(4))) f16 f16x4;
typedef __attribute__((ext_vector_type(4))) float f32x4;

constexpr int N = 1024;

__device__ __forceinline__ float leaky(float v) { return v >= 0.f ? v : 0.01f * v; }

__device__ __forceinline__ void dma16(const void* g, void* l) {
    __builtin_amdgcn_global_load_lds(
        (const __attribute__((address_space(1))) uint32_t*)g,
        (__attribute__((address_space(3))) uint32_t*)l, 16, 0, 0);
}

// ---------------------------------------------------------------------------
// Unified GEMM for BinaryTreeConv (SEGS=3, gather) and ChannelMixer (SEGS=1).
// r20 -> r22: SMALLER BARRIER DOMAINS at constant waves/CU. 256-thread
// blocks (4 waves) with the identical per-wave shape: LDS/block ~17.4KB and
// VGPR<=64 -> 8 blocks/CU x 4 waves = 32 waves/CU (same as before), but each
// __syncthreads only gangs 4 waves — 8 independent groups per CU cover each
// other's staging drains (m114 wave-overlap, zero extra registers — the
// r18/r19/r21 pipelining attempts all died by VGPR/occupancy).
// W staged per phase (KS32=1 for convs -> 16KB stages), A direct->register
// with depth-3 rotation prefetch, LDS-transposed epilogue, inline LN stats.
// Block: 256 threads = 4 waves; tile (64*RT)n x (UW*16)o.
// ---------------------------------------------------------------------------
template<int CI, int CO, int SEGS, int NSTG, int UW, int RT, bool ISMIX>
__global__ __launch_bounds__(256) void gemm_kernel(
    const f16* __restrict__ X, const int* __restrict__ idx,
    const f16* __restrict__ Wf, const float* __restrict__ bias,
    f16* __restrict__ Y, float2* __restrict__ part,
    const float2* __restrict__ pin, int nparts, float Mf)
{
    constexpr int THREADS = 256;
    constexpr int NW = THREADS / 64;                // 4 waves
    constexpr int SKT = SEGS * CI / 32;             // total k-chunks of 32
    constexpr int KS32 = (SKT + NSTG - 1) / NSTG;   // k-chunks per phase (ceil)
    constexpr int Ug = CO / 16;                     // global o-subtile count
    constexpr int NGRAN = KS32 * UW * 64;           // 16B granules per phase
    constexpr int SBYTES = NGRAN * 16;              // staging bytes
    constexpr int EBYTES = NW * 16 * 68 * 4;        // epilogue slabs (4 waves)
    constexpr int LBYTES = SBYTES > EBYTES ? SBYTES : EBYTES;
    static_assert(CI % 32 == 0 && UW % 4 == 0, "geometry");
    static_assert(RT == 1 || RT == 2, "rt");

    __shared__ alignas(16) char ldsraw[LBYTES];
    __shared__ float redu[2 * NW];

    const int tid = threadIdx.x;
    const int w = tid >> 6, l = tid & 63;
    const int n0 = blockIdx.x * (64 * RT);    // n fastest (measured best)
    const int u0 = blockIdx.y * UW;
    const int b  = blockIdx.z;
    const int g  = blockIdx.x + gridDim.x * blockIdx.y;

    // per-lane A-row indices (gather for conv, identity for mix)
    int rows[RT][SEGS];
    #pragma unroll
    for (int rt = 0; rt < RT; ++rt) {
        int n = n0 + 16 * (RT * w + rt) + (l & 15);
        if constexpr (ISMIX) {
            rows[rt][0] = n;
        } else {
            const int* ip = idx + (size_t)b * 3 * N + 3 * n;
            #pragma unroll
            for (int s = 0; s < SEGS; ++s) rows[rt][s] = ip[s];
        }
    }
    const f16* xb = X + (size_t)b * N * CI;
    const int koff = 8 * (l >> 4);

    // inline LN stats (mix only): plain loads of the previous conv's partials
    float2 st = make_float2(0.f, 0.f);
    if constexpr (ISMIX) {
        float s1 = 0.f, s2 = 0.f;
        for (int i = 0; i < nparts; ++i) {
            float2 p = pin[(size_t)b * 16 + i];
            s1 += p.x; s2 += p.y;
        }
        float mu = s1 / Mf;
        float var = fmaxf((s2 - s1 * s1 / Mf) / (Mf - 1.f), 0.f);   // ddof = 1
        st = make_float2(mu, 1.f / (sqrtf(var) + 1e-5f));
    }

    const f16* lds = (const f16*)ldsraw;

    auto stageW = [&](int pp) {
        for (int gg = tid; gg < NGRAN; gg += THREADS) {
            int skk = gg / (UW * 64);
            int uu = (gg >> 6) % UW;
            int ll = gg & 63;
            int skg = pp * KS32 + skk;                 // wave-uniform guard
            if (skg < SKT)
                dma16(Wf + (((size_t)skg * Ug + u0 + uu) * 64 + ll) * 8,
                      ldsraw + (size_t)gg * 16);
        }
    };

    f16x8 pa[RT][3];
    auto loadA = [&](int sk, int d) {
        const int seg = (sk * 32) / CI;                  // compile-time
        const int co = sk * 32 - seg * CI + koff;
        #pragma unroll
        for (int rt = 0; rt < RT; ++rt)
            pa[rt][d] = *(const f16x8*)(xb + (size_t)rows[rt][seg] * CI + co);
    };

    if constexpr (NSTG == 1) stageW(0);

    constexpr int D = SKT < 3 ? SKT : 3;
    #pragma unroll
    for (int d = 0; d < D; ++d) loadA(d, d);

    if constexpr (NSTG == 1) __syncthreads();

    f32x4 acc[RT][UW] = {};

    #pragma unroll
    for (int pp = 0; pp < NSTG; ++pp) {
        if constexpr (NSTG > 1) { stageW(pp); __syncthreads(); }

        #pragma unroll
        for (int skl = 0; skl < KS32; ++skl) {
            const int sk = pp * KS32 + skl;
            if (sk >= SKT) break;                       // compile-time tail guard
            f16x8 av[RT];
            #pragma unroll
            for (int rt = 0; rt < RT; ++rt) av[rt] = pa[rt][sk % 3];
            if (sk + 3 < SKT) loadA(sk + 3, sk % 3);
            #pragma unroll
            for (int uu = 0; uu < UW; ++uu) {
                f16x8 wv = *(const f16x8*)(lds + ((size_t)(skl * UW + uu) * 64 + l) * 8);
                #pragma unroll
                for (int rt = 0; rt < RT; ++rt)
                    acc[rt][uu] = __builtin_amdgcn_mfma_f32_16x16x32_f16(av[rt], wv, acc[rt][uu], 0, 0, 0);
            }
        }
        if (pp + 1 < NSTG) __syncthreads();   // before next stage overwrites
    }

    __syncthreads();   // staging region reused as epilogue slabs

    // ---- LDS-transposed epilogue: coalesced f16x8 global accesses ----
    float (*ep)[68] = (float(*)[68])(ldsraw + w * 4352);   // [16][68] per wave
    float ps1 = 0.f, ps2 = 0.f;

    #pragma unroll
    for (int rt = 0; rt < RT; ++rt) {
        #pragma unroll
        for (int E = 0; E < UW / 4; ++E) {
            asm volatile("s_waitcnt lgkmcnt(0)" ::: "memory");  // prior reads done (WAR)
            #pragma unroll
            for (int u4 = 0; u4 < 4; ++u4)
                #pragma unroll
                for (int j = 0; j < 4; ++j)
                    ep[4 * (l >> 4) + j][u4 * 16 + (l & 15)] = acc[rt][E * 4 + u4][j];
            asm volatile("s_waitcnt lgkmcnt(0)" ::: "memory");  // writes visible
            __builtin_amdgcn_sched_barrier(0);
            #pragma unroll
            for (int ci = 0; ci < 2; ++ci) {
                int c = l + 64 * ci;
                int r = c >> 3, oc = (c & 7) * 8;
                int ob = u0 * 16 + E * 64 + oc;
                int n = n0 + 16 * (RT * w + rt) + r;
                size_t yoff = ((size_t)b * N + n) * CO + ob;
                float v[8];
                #pragma unroll
                for (int k = 0; k < 8; ++k) v[k] = ep[r][oc + k] + bias[ob + k];
                f16x8 rv;
                if constexpr (!ISMIX) {
                    #pragma unroll
                    for (int k = 0; k < 8; ++k) {
                        ps1 += v[k]; ps2 += v[k] * v[k];
                        rv[k] = (f16)v[k];
                    }
                } else {
                    f16x8 yc = *(const f16x8*)(Y + yoff);
                    #pragma unroll
                    for (int k = 0; k < 8; ++k)
                        rv[k] = (f16)leaky(v[k] + ((float)yc[k] - st.x) * st.y);
                }
                *(f16x8*)(Y + yoff) = rv;
            }
        }
    }

    if constexpr (!ISMIX) {
        #pragma unroll
        for (int m = 32; m; m >>= 1) { ps1 += __shfl_xor(ps1, m); ps2 += __shfl_xor(ps2, m); }
        if (l == 0) { redu[w * 2] = ps1; redu[w * 2 + 1] = ps2; }
        __syncthreads();
        if (tid == 0) {
            float t1 = 0.f, t2 = 0.f;
            #pragma unroll
            for (int k = 0; k < NW; ++k) { t1 += redu[2 * k]; t2 += redu[2 * k + 1]; }
            part[(size_t)b * 16 + g] = make_float2(t1, t2);
        }
    }
}

// fp32 [B][160][N] -> f16 [B][N][160], float4 (16B/lane) loads
__global__ __launch_bounds__(256) void transpose_kernel(
    const float* __restrict__ trees, f16* __restrict__ X0)
{
    __shared__ f16 tile[32][68];
    int b = blockIdx.z, c0 = blockIdx.y * 32, n0 = blockIdx.x * 64;
    int tid = threadIdx.x;
    #pragma unroll
    for (int r = 0; r < 2; ++r) {
        int s = tid + 256 * r;
        int c = s >> 4, nq = (s & 15) * 4;
        float4 v = *(const float4*)&trees[((size_t)b * 160 + c0 + c) * N + n0 + nq];
        f16x4 h; h[0] = (f16)v.x; h[1] = (f16)v.y; h[2] = (f16)v.z; h[3] = (f16)v.w;
        *(f16x4*)&tile[c][nq] = h;
    }
    __syncthreads();
    int nn = tid >> 2, gc = tid & 3;
    f16x8 pack;
    #pragma unroll
    for (int e = 0; e < 8; ++e) pack[e] = tile[gc * 8 + e][nn];
    *(f16x8*)(X0 + ((size_t)b * N + n0 + nn) * 160 + c0 + gc * 8) = pack;
}

// all six weight preps in ONE launch (no atomics, no counters).
// fragment layout: elem ((skk*U+u)*64+l)*8+j holds W[kap=32*skk+8*(l>>4)+j][o=16u+(l&15)],
// kappa-order kap = k*CI + c for conv.
__device__ __forceinline__ void prepW_one(
    const float* __restrict__ Wsrc, f16* __restrict__ out,
    int e, int CO, int CI, int isconv)
{
    int j = e & 7, l = (e >> 3) & 63, r = e >> 9;
    int U = CO / 16;
    int u = r % U, t = r / U;
    int kap = 32 * t + 8 * (l >> 4) + j;
    int o = 16 * u + (l & 15);
    float v = isconv ? Wsrc[((size_t)o * CI + (kap % CI)) * 3 + kap / CI]
                     : Wsrc[(size_t)o * CI + kap];
    out[e] = (f16)v;
}

__global__ __launch_bounds__(256) void prepW6_kernel(
    const float* Wc1, const float* Wm1, const float* Wc2, const float* Wm2,
    const float* Wc3, const float* Wm3,
    f16* o1, f16* m1, f16* o2, f16* m2, f16* o3, f16* m3)
{
    int bx = blockIdx.x;
    if (bx < 480)       prepW_one(Wc1, o1, (bx -    0) * 256 + threadIdx.x, 256, 160, 1);
    else if (bx < 640)  prepW_one(Wm1, m1, (bx -  480) * 256 + threadIdx.x, 256, 160, 0);
    else if (bx < 1024) prepW_one(Wc2, o2, (bx -  640) * 256 + threadIdx.x, 128, 256, 1);
    else if (bx < 1152) prepW_one(Wm2, m2, (bx - 1024) * 256 + threadIdx.x, 128, 256, 0);
    else if (bx < 1248) prepW_one(Wc3, o3, (bx - 1152) * 256 + threadIdx.x,  64, 128, 1);
    else                prepW_one(Wm3, m3, (bx - 1248) * 256 + threadIdx.x,  64, 128, 0);
}

// masked max-pool + 64->32->1 MLP; x3 is [b][n][64] f16. f16x8 (16B/lane) reads.
__global__ __launch_bounds__(256) void final_kernel(
    const f16* __restrict__ x3, const int* __restrict__ nodes,
    const float* __restrict__ W1, const float* __restrict__ b1,
    const float* __restrict__ W2, const float* __restrict__ b2,
    float* __restrict__ out)
{
    int b = blockIdx.x, tid = threadIdx.x;
    int oq = (tid & 7) * 8, rr = tid >> 3;      // 32 n-strides x 8 o-octets
    int nv = nodes[b];
    const f16* p = x3 + (size_t)b * N * 64 + oq;
    float mx[8];
    #pragma unroll
    for (int k = 0; k < 8; ++k) mx[k] = -3.4e38f;
    for (int n = rr; n < nv; n += 32) {
        f16x8 v = *(const f16x8*)(p + (size_t)n * 64);
        #pragma unroll
        for (int k = 0; k < 8; ++k) mx[k] = fmaxf(mx[k], (float)v[k]);
    }
    __shared__ float pool[32][64];
    __shared__ float pooled[64], hbuf[32];
    #pragma unroll
    for (int k = 0; k < 8; ++k) pool[rr][oq + k] = mx[k];
    __syncthreads();
    if (tid < 64) {
        float m = pool[0][tid];
        #pragma unroll 8
        for (int r = 1; r < 32; ++r) m = fmaxf(m, pool[r][tid]);
        pooled[tid] = m;
    }
    __syncthreads();
    if (tid < 32) {
        float h = b1[tid];
        #pragma unroll 8
        for (int oo = 0; oo < 64; ++oo) h += pooled[oo] * W1[oo * 32 + tid];
        hbuf[tid] = leaky(h);
    }
    __syncthreads();
    if (tid == 0) {
        float rr2 = b2[0];
        for (int jj = 0; jj < 32; ++jj) rr2 += hbuf[jj] * W2[jj];
        out[b] = rr2;
    }
}

extern "C" void kernel_launch(void* const* d_in, const int* in_sizes, int n_in,
                              void* d_out, int out_size, void* d_ws, size_t ws_size,
                              hipStream_t stream)
{
    (void)in_sizes; (void)n_in; (void)out_size; (void)ws_size;
    const float* trees = (const float*)d_in[0];
    const int* indexes = (const int*)d_in[1];
    const int* nodes   = (const int*)d_in[2];
    const float* Wc1 = (const float*)d_in[3];
    const float* bc1 = (const float*)d_in[4];
    const float* Wm1 = (const float*)d_in[5];
    const float* bm1 = (const float*)d_in[6];
    const float* Wc2 = (const float*)d_in[7];
    const float* bc2 = (const float*)d_in[8];
    const float* Wm2 = (const float*)d_in[9];
    const float* bm2 = (const float*)d_in[10];
    const float* Wc3 = (const float*)d_in[11];
    const float* bc3 = (const float*)d_in[12];
    const float* Wm3 = (const float*)d_in[13];
    const float* bm3 = (const float*)d_in[14];
    const float* W1 = (const float*)d_in[15];
    const float* b1 = (const float*)d_in[16];
    const float* W2 = (const float*)d_in[17];
    const float* b2 = (const float*)d_in[18];
    float* out = (float*)d_out;

    // ws layout:
    //   [0, 83886080)            X0 [B][N][160] f16      -> later yc2/x2 (67MB)
    //   [83886080, 218103808)    yc1/x1 [B][N][256] f16  -> later yc3/x3 (33.5MB)
    //   [218103808, ...)         Wfrags, parts
    char* ws = (char*)d_ws;
    f16* X0 = (f16*)ws;
    f16* A1 = (f16*)(ws + 83886080);
    f16* A2 = (f16*)ws;
    f16* A3 = A1;
    size_t toff = 218103808;
    f16* Wfc1 = (f16*)(ws + toff); toff += (size_t)480 * 256 * 2;
    f16* Wfm1 = (f16*)(ws + toff); toff += (size_t)160 * 256 * 2;
    f16* Wfc2 = (f16*)(ws + toff); toff += (size_t)768 * 128 * 2;
    f16* Wfm2 = (f16*)(ws + toff); toff += (size_t)256 * 128 * 2;
    f16* Wfc3 = (f16*)(ws + toff); toff += (size_t)384 * 64 * 2;
    f16* Wfm3 = (f16*)(ws + toff); toff += (size_t)128 * 64 * 2;
    float2* part  = (float2*)(ws + toff);

    transpose_kernel<<<dim3(16, 5, 256), 256, 0, stream>>>(trees, X0);
    prepW6_kernel<<<1280, 256, 0, stream>>>(Wc1, Wm1, Wc2, Wm2, Wc3, Wm3,
                                            Wfc1, Wfm1, Wfc2, Wfm2, Wfc3, Wfm3);

    // 256-thread blocks, 64-n tiles, full CO per block (16 n-tiles -> g<16)
    // layer 1: conv NSTG=15 (KS32=1, 16KB stage); mix NSTG=5 (16KB)
    gemm_kernel<160, 256, 3, 15, 16, 1, false><<<dim3(16, 1, 256), 256, 0, stream>>>(
        X0, indexes, Wfc1, bc1, A1, part, nullptr, 0, 0.f);
    gemm_kernel<160, 256, 1, 5, 16, 1, true><<<dim3(16, 1, 256), 256, 0, stream>>>(
        X0, nullptr, Wfm1, bm1, A1, nullptr, part, 16, 262144.f);

    // layer 2: conv NSTG=24 (KS32=1, 8KB); mix NSTG=8 (KS32=1, 8KB)
    gemm_kernel<256, 128, 3, 24, 8, 1, false><<<dim3(16, 1, 256), 256, 0, stream>>>(
        A1, indexes, Wfc2, bc2, A2, part, nullptr, 0, 0.f);
    gemm_kernel<256, 128, 1, 8, 8, 1, true><<<dim3(16, 1, 256), 256, 0, stream>>>(
        A1, nullptr, Wfm2, bm2, A2, nullptr, part, 16, 131072.f);

    // layer 3: conv NSTG=12 (KS32=1, 4KB); mix NSTG=1 (single 16KB stage)
    gemm_kernel<128, 64, 3, 12, 4, 1, false><<<dim3(16, 1, 256), 256, 0, stream>>>(
        A2, indexes, Wfc3, bc3, A3, part, nullptr, 0, 0.f);
    gemm_kernel<128, 64, 1, 1, 4, 1, true><<<dim3(16, 1, 256), 256, 0, stream>>>(
        A2, nullptr, Wfm3, bm3, A3, nullptr, part, 16, 65536.f);

    final_kernel<<<256, 256, 0, stream>>>(A3, nodes, W1, b1, W2, b2, out);
}

// Round 23
// 415.391 us; speedup vs baseline: 1.1344x; 1.1344x over previous
//
#include <hip/hip_runtime.h>
#include <stdint.h>

using f16 = _Float16;
typedef __attribute__((ext_vector_type(8))) f16 f16x8;
typedef __attribute__((ext_vector_type(4))) f16 f16x4;
typedef __attribute__((ext_vector_type(4))) float f32x4;

constexpr int N = 1024;

__device__ __forceinline__ float leaky(float v) { return v >= 0.f ? v : 0.01f * v; }

__device__ __forceinline__ void dma16(const void* g, void* l) {
    __builtin_amdgcn_global_load_lds(
        (const __attribute__((address_space(1))) uint32_t*)g,
        (__attribute__((address_space(3))) uint32_t*)l, 16, 0, 0);
}

// ---------------------------------------------------------------------------
// Unified GEMM for BinaryTreeConv (SEGS=3, gather) and ChannelMixer (SEGS=1).
// FINAL (r23 = r17/r20 fixed point). Perturbation history, all measured:
//   r18 counted-vmcnt PIPE: raced (A-loads hoist over dma16).
//   r19 region-safe PIPE:   correct but VGPR 60->128 + spills -> 182us.
//   r21 plain double-buffer: VGPR 60->76 -> 2 blk/CU -> 139us.
//   r22 256-thread blocks:  VGPR 104 -> 21% occupancy -> 147us.
// Conclusion: {512 threads, RT=1, VGPR<=64, LDS<=35KB, 4 blk/CU, per-phase
// __syncthreads drain} is the empirical optimum of this structure. The
// residual conv gap (~2.3x BW floor, both pipes <35%) is the staging-drain
// latency; every removal mechanism costs more occupancy than it saves.
// Structure: W staged to LDS in NSTG ceil-phases; A-fragments direct
// global->register with depth-3 rotation prefetch; LDS-transposed epilogue
// (fully-coalesced f16x8 IO); mix kernels compute LN stats inline from the
// conv's per-block partials (plain loads, stream-ordered; NO device-scope
// atomics — r10 showed those thrash the non-coherent per-XCD L2s).
// Block: 512 threads = 8 waves; tile (128*RT)n x (UW*16)o.
// ---------------------------------------------------------------------------
template<int CI, int CO, int SEGS, int NSTG, int UW, int RT, bool ISMIX>
__global__ __launch_bounds__(512) void gemm_kernel(
    const f16* __restrict__ X, const int* __restrict__ idx,
    const f16* __restrict__ Wf, const float* __restrict__ bias,
    f16* __restrict__ Y, float2* __restrict__ part,
    const float2* __restrict__ pin, int nparts, float Mf)
{
    constexpr int SKT = SEGS * CI / 32;             // total k-chunks of 32
    constexpr int KS32 = (SKT + NSTG - 1) / NSTG;   // k-chunks per phase (ceil)
    constexpr int Ug = CO / 16;                     // global o-subtile count
    constexpr int NGRAN = KS32 * UW * 64;           // 16B granules per phase
    constexpr int SBYTES = NGRAN * 16;              // staging bytes
    constexpr int EBYTES = 8 * 16 * 68 * 4;         // epilogue slabs (8 waves)
    constexpr int LBYTES = SBYTES > EBYTES ? SBYTES : EBYTES;
    static_assert(CI % 32 == 0 && UW % 4 == 0, "geometry");
    static_assert(RT == 1 || RT == 2, "rt");

    __shared__ alignas(16) char ldsraw[LBYTES];
    __shared__ float redu[16];

    const int tid = threadIdx.x;
    const int w = tid >> 6, l = tid & 63;
    const int n0 = blockIdx.x * (128 * RT);   // n fastest (measured best)
    const int u0 = blockIdx.y * UW;
    const int b  = blockIdx.z;
    const int g  = blockIdx.x + gridDim.x * blockIdx.y;

    // per-lane A-row indices (gather for conv, identity for mix)
    int rows[RT][SEGS];
    #pragma unroll
    for (int rt = 0; rt < RT; ++rt) {
        int n = n0 + 16 * (RT * w + rt) + (l & 15);
        if constexpr (ISMIX) {
            rows[rt][0] = n;
        } else {
            const int* ip = idx + (size_t)b * 3 * N + 3 * n;
            #pragma unroll
            for (int s = 0; s < SEGS; ++s) rows[rt][s] = ip[s];
        }
    }
    const f16* xb = X + (size_t)b * N * CI;
    const int koff = 8 * (l >> 4);

    // inline LN stats (mix only): plain loads of the previous conv's partials
    float2 st = make_float2(0.f, 0.f);
    if constexpr (ISMIX) {
        float s1 = 0.f, s2 = 0.f;
        for (int i = 0; i < nparts; ++i) {
            float2 p = pin[(size_t)b * 16 + i];
            s1 += p.x; s2 += p.y;
        }
        float mu = s1 / Mf;
        float var = fmaxf((s2 - s1 * s1 / Mf) / (Mf - 1.f), 0.f);   // ddof = 1
        st = make_float2(mu, 1.f / (sqrtf(var) + 1e-5f));
    }

    const f16* lds = (const f16*)ldsraw;

    auto stageW = [&](int pp) {
        for (int gg = tid; gg < NGRAN; gg += 512) {
            int skk = gg / (UW * 64);
            int uu = (gg >> 6) % UW;
            int ll = gg & 63;
            int skg = pp * KS32 + skk;                 // wave-uniform guard
            if (skg < SKT)
                dma16(Wf + (((size_t)skg * Ug + u0 + uu) * 64 + ll) * 8,
                      ldsraw + (size_t)gg * 16);
        }
    };

    f16x8 pa[RT][3];
    auto loadA = [&](int sk, int d) {
        const int seg = (sk * 32) / CI;                  // compile-time
        const int co = sk * 32 - seg * CI + koff;
        #pragma unroll
        for (int rt = 0; rt < RT; ++rt)
            pa[rt][d] = *(const f16x8*)(xb + (size_t)rows[rt][seg] * CI + co);
    };

    if constexpr (NSTG == 1) stageW(0);

    constexpr int D = SKT < 3 ? SKT : 3;
    #pragma unroll
    for (int d = 0; d < D; ++d) loadA(d, d);

    if constexpr (NSTG == 1) __syncthreads();

    f32x4 acc[RT][UW] = {};

    #pragma unroll
    for (int pp = 0; pp < NSTG; ++pp) {
        if constexpr (NSTG > 1) { stageW(pp); __syncthreads(); }

        #pragma unroll
        for (int skl = 0; skl < KS32; ++skl) {
            const int sk = pp * KS32 + skl;
            if (sk >= SKT) break;                       // compile-time tail guard
            f16x8 av[RT];
            #pragma unroll
            for (int rt = 0; rt < RT; ++rt) av[rt] = pa[rt][sk % 3];
            if (sk + 3 < SKT) loadA(sk + 3, sk % 3);
            #pragma unroll
            for (int uu = 0; uu < UW; ++uu) {
                f16x8 wv = *(const f16x8*)(lds + ((size_t)(skl * UW + uu) * 64 + l) * 8);
                #pragma unroll
                for (int rt = 0; rt < RT; ++rt)
                    acc[rt][uu] = __builtin_amdgcn_mfma_f32_16x16x32_f16(av[rt], wv, acc[rt][uu], 0, 0, 0);
            }
        }
        if (pp + 1 < NSTG) __syncthreads();   // before next stage overwrites
    }

    __syncthreads();   // staging region reused as epilogue slabs

    // ---- LDS-transposed epilogue: coalesced f16x8 global accesses ----
    float (*ep)[68] = (float(*)[68])(ldsraw + w * 4352);   // [16][68] per wave
    float ps1 = 0.f, ps2 = 0.f;

    #pragma unroll
    for (int rt = 0; rt < RT; ++rt) {
        #pragma unroll
        for (int E = 0; E < UW / 4; ++E) {
            asm volatile("s_waitcnt lgkmcnt(0)" ::: "memory");  // prior reads done (WAR)
            #pragma unroll
            for (int u4 = 0; u4 < 4; ++u4)
                #pragma unroll
                for (int j = 0; j < 4; ++j)
                    ep[4 * (l >> 4) + j][u4 * 16 + (l & 15)] = acc[rt][E * 4 + u4][j];
            asm volatile("s_waitcnt lgkmcnt(0)" ::: "memory");  // writes visible
            __builtin_amdgcn_sched_barrier(0);
            #pragma unroll
            for (int ci = 0; ci < 2; ++ci) {
                int c = l + 64 * ci;
                int r = c >> 3, oc = (c & 7) * 8;
                int ob = u0 * 16 + E * 64 + oc;
                int n = n0 + 16 * (RT * w + rt) + r;
                size_t yoff = ((size_t)b * N + n) * CO + ob;
                float v[8];
                #pragma unroll
                for (int k = 0; k < 8; ++k) v[k] = ep[r][oc + k] + bias[ob + k];
                f16x8 rv;
                if constexpr (!ISMIX) {
                    #pragma unroll
                    for (int k = 0; k < 8; ++k) {
                        ps1 += v[k]; ps2 += v[k] * v[k];
                        rv[k] = (f16)v[k];
                    }
                } else {
                    f16x8 yc = *(const f16x8*)(Y + yoff);
                    #pragma unroll
                    for (int k = 0; k < 8; ++k)
                        rv[k] = (f16)leaky(v[k] + ((float)yc[k] - st.x) * st.y);
                }
                *(f16x8*)(Y + yoff) = rv;
            }
        }
    }

    if constexpr (!ISMIX) {
        #pragma unroll
        for (int m = 32; m; m >>= 1) { ps1 += __shfl_xor(ps1, m); ps2 += __shfl_xor(ps2, m); }
        if (l == 0) { redu[w * 2] = ps1; redu[w * 2 + 1] = ps2; }
        __syncthreads();
        if (tid == 0) {
            float t1 = 0.f, t2 = 0.f;
            #pragma unroll
            for (int k = 0; k < 8; ++k) { t1 += redu[2 * k]; t2 += redu[2 * k + 1]; }
            part[(size_t)b * 16 + g] = make_float2(t1, t2);
        }
    }
}

// fp32 [B][160][N] -> f16 [B][N][160], float4 (16B/lane) loads
__global__ __launch_bounds__(256) void transpose_kernel(
    const float* __restrict__ trees, f16* __restrict__ X0)
{
    __shared__ f16 tile[32][68];
    int b = blockIdx.z, c0 = blockIdx.y * 32, n0 = blockIdx.x * 64;
    int tid = threadIdx.x;
    #pragma unroll
    for (int r = 0; r < 2; ++r) {
        int s = tid + 256 * r;
        int c = s >> 4, nq = (s & 15) * 4;
        float4 v = *(const float4*)&trees[((size_t)b * 160 + c0 + c) * N + n0 + nq];
        f16x4 h; h[0] = (f16)v.x; h[1] = (f16)v.y; h[2] = (f16)v.z; h[3] = (f16)v.w;
        *(f16x4*)&tile[c][nq] = h;
    }
    __syncthreads();
    int nn = tid >> 2, gc = tid & 3;
    f16x8 pack;
    #pragma unroll
    for (int e = 0; e < 8; ++e) pack[e] = tile[gc * 8 + e][nn];
    *(f16x8*)(X0 + ((size_t)b * N + n0 + nn) * 160 + c0 + gc * 8) = pack;
}

// all six weight preps in ONE launch (no atomics, no counters).
// fragment layout: elem ((skk*U+u)*64+l)*8+j holds W[kap=32*skk+8*(l>>4)+j][o=16u+(l&15)],
// kappa-order kap = k*CI + c for conv.
__device__ __forceinline__ void prepW_one(
    const float* __restrict__ Wsrc, f16* __restrict__ out,
    int e, int CO, int CI, int isconv)
{
    int j = e & 7, l = (e >> 3) & 63, r = e >> 9;
    int U = CO / 16;
    int u = r % U, t = r / U;
    int kap = 32 * t + 8 * (l >> 4) + j;
    int o = 16 * u + (l & 15);
    float v = isconv ? Wsrc[((size_t)o * CI + (kap % CI)) * 3 + kap / CI]
                     : Wsrc[(size_t)o * CI + kap];
    out[e] = (f16)v;
}

__global__ __launch_bounds__(256) void prepW6_kernel(
    const float* Wc1, const float* Wm1, const float* Wc2, const float* Wm2,
    const float* Wc3, const float* Wm3,
    f16* o1, f16* m1, f16* o2, f16* m2, f16* o3, f16* m3)
{
    int bx = blockIdx.x;
    if (bx < 480)       prepW_one(Wc1, o1, (bx -    0) * 256 + threadIdx.x, 256, 160, 1);
    else if (bx < 640)  prepW_one(Wm1, m1, (bx -  480) * 256 + threadIdx.x, 256, 160, 0);
    else if (bx < 1024) prepW_one(Wc2, o2, (bx -  640) * 256 + threadIdx.x, 128, 256, 1);
    else if (bx < 1152) prepW_one(Wm2, m2, (bx - 1024) * 256 + threadIdx.x, 128, 256, 0);
    else if (bx < 1248) prepW_one(Wc3, o3, (bx - 1152) * 256 + threadIdx.x,  64, 128, 1);
    else                prepW_one(Wm3, m3, (bx - 1248) * 256 + threadIdx.x,  64, 128, 0);
}

// masked max-pool + 64->32->1 MLP; x3 is [b][n][64] f16. f16x8 (16B/lane) reads.
__global__ __launch_bounds__(256) void final_kernel(
    const f16* __restrict__ x3, const int* __restrict__ nodes,
    const float* __restrict__ W1, const float* __restrict__ b1,
    const float* __restrict__ W2, const float* __restrict__ b2,
    float* __restrict__ out)
{
    int b = blockIdx.x, tid = threadIdx.x;
    int oq = (tid & 7) * 8, rr = tid >> 3;      // 32 n-strides x 8 o-octets
    int nv = nodes[b];
    const f16* p = x3 + (size_t)b * N * 64 + oq;
    float mx[8];
    #pragma unroll
    for (int k = 0; k < 8; ++k) mx[k] = -3.4e38f;
    for (int n = rr; n < nv; n += 32) {
        f16x8 v = *(const f16x8*)(p + (size_t)n * 64);
        #pragma unroll
        for (int k = 0; k < 8; ++k) mx[k] = fmaxf(mx[k], (float)v[k]);
    }
    __shared__ float pool[32][64];
    __shared__ float pooled[64], hbuf[32];
    #pragma unroll
    for (int k = 0; k < 8; ++k) pool[rr][oq + k] = mx[k];
    __syncthreads();
    if (tid < 64) {
        float m = pool[0][tid];
        #pragma unroll 8
        for (int r = 1; r < 32; ++r) m = fmaxf(m, pool[r][tid]);
        pooled[tid] = m;
    }
    __syncthreads();
    if (tid < 32) {
        float h = b1[tid];
        #pragma unroll 8
        for (int oo = 0; oo < 64; ++oo) h += pooled[oo] * W1[oo * 32 + tid];
        hbuf[tid] = leaky(h);
    }
    __syncthreads();
    if (tid == 0) {
        float rr2 = b2[0];
        for (int jj = 0; jj < 32; ++jj) rr2 += hbuf[jj] * W2[jj];
        out[b] = rr2;
    }
}

extern "C" void kernel_launch(void* const* d_in, const int* in_sizes, int n_in,
                              void* d_out, int out_size, void* d_ws, size_t ws_size,
                              hipStream_t stream)
{
    (void)in_sizes; (void)n_in; (void)out_size; (void)ws_size;
    const float* trees = (const float*)d_in[0];
    const int* indexes = (const int*)d_in[1];
    const int* nodes   = (const int*)d_in[2];
    const float* Wc1 = (const float*)d_in[3];
    const float* bc1 = (const float*)d_in[4];
    const float* Wm1 = (const float*)d_in[5];
    const float* bm1 = (const float*)d_in[6];
    const float* Wc2 = (const float*)d_in[7];
    const float* bc2 = (const float*)d_in[8];
    const float* Wm2 = (const float*)d_in[9];
    const float* bm2 = (const float*)d_in[10];
    const float* Wc3 = (const float*)d_in[11];
    const float* bc3 = (const float*)d_in[12];
    const float* Wm3 = (const float*)d_in[13];
    const float* bm3 = (const float*)d_in[14];
    const float* W1 = (const float*)d_in[15];
    const float* b1 = (const float*)d_in[16];
    const float* W2 = (const float*)d_in[17];
    const float* b2 = (const float*)d_in[18];
    float* out = (float*)d_out;

    // ws layout:
    //   [0, 83886080)            X0 [B][N][160] f16      -> later yc2/x2 (67MB)
    //   [83886080, 218103808)    yc1/x1 [B][N][256] f16  -> later yc3/x3 (33.5MB)
    //   [218103808, ...)         Wfrags, parts
    char* ws = (char*)d_ws;
    f16* X0 = (f16*)ws;
    f16* A1 = (f16*)(ws + 83886080);
    f16* A2 = (f16*)ws;
    f16* A3 = A1;
    size_t toff = 218103808;
    f16* Wfc1 = (f16*)(ws + toff); toff += (size_t)480 * 256 * 2;
    f16* Wfm1 = (f16*)(ws + toff); toff += (size_t)160 * 256 * 2;
    f16* Wfc2 = (f16*)(ws + toff); toff += (size_t)768 * 128 * 2;
    f16* Wfm2 = (f16*)(ws + toff); toff += (size_t)256 * 128 * 2;
    f16* Wfc3 = (f16*)(ws + toff); toff += (size_t)384 * 64 * 2;
    f16* Wfm3 = (f16*)(ws + toff); toff += (size_t)128 * 64 * 2;
    float2* part  = (float2*)(ws + toff);

    transpose_kernel<<<dim3(16, 5, 256), 256, 0, stream>>>(trees, X0);
    prepW6_kernel<<<1280, 256, 0, stream>>>(Wc1, Wm1, Wc2, Wm2, Wc3, Wm3,
                                            Wfc1, Wfm1, Wfc2, Wfm2, Wfc3, Wfm3);

    // layer 1: conv RT=1,UW=16 full-CO, NSTG=8 (KS32=2, 32KB -> 4 blk/CU);
    //          mix RT=1,UW=16 full-CO, NSTG=5
    gemm_kernel<160, 256, 3, 8, 16, 1, false><<<dim3(8, 1, 256), 512, 0, stream>>>(
        X0, indexes, Wfc1, bc1, A1, part, nullptr, 0, 0.f);
    gemm_kernel<160, 256, 1, 5, 16, 1, true><<<dim3(8, 1, 256), 512, 0, stream>>>(
        X0, nullptr, Wfm1, bm1, A1, nullptr, part, 8, 262144.f);

    // layer 2: conv RT=1,UW=8 full-CO, NSTG=6 (KS32=4, 32KB); mix RT=1,UW=8, NSTG=2
    gemm_kernel<256, 128, 3, 6, 8, 1, false><<<dim3(8, 1, 256), 512, 0, stream>>>(
        A1, indexes, Wfc2, bc2, A2, part, nullptr, 0, 0.f);
    gemm_kernel<256, 128, 1, 2, 8, 1, true><<<dim3(8, 1, 256), 512, 0, stream>>>(
        A1, nullptr, Wfm2, bm2, A2, nullptr, part, 8, 131072.f);

    // layer 3: conv RT=1,UW=4 full-CO, NSTG=2 (24KB); mix RT=1,UW=4, NSTG=1
    gemm_kernel<128, 64, 3, 2, 4, 1, false><<<dim3(8, 1, 256), 512, 0, stream>>>(
        A2, indexes, Wfc3, bc3, A3, part, nullptr, 0, 0.f);
    gemm_kernel<128, 64, 1, 1, 4, 1, true><<<dim3(8, 1, 256), 512, 0, stream>>>(
        A2, nullptr, Wfm3, bm3, A3, nullptr, part, 8, 65536.f);

    final_kernel<<<256, 256, 0, stream>>>(A3, nodes, W1, b1, W2, b2, out);
}